// Round 4
// baseline (168.835 us; speedup 1.0000x reference)
//
#include <hip/hip_runtime.h>
#include <stdint.h>

#define EPSF 1e-6f

// ---------------------------------------------------------------------------
// DPP full-wave (64-lane) sum. After this, lane 63 holds the wave total.
// All VALU-pipe — no ds_bpermute, no LDS traffic.
// ---------------------------------------------------------------------------
__device__ __forceinline__ float wave_sum_to_lane63(float x) {
  x += __int_as_float(__builtin_amdgcn_update_dpp(0, __float_as_int(x), 0x111, 0xf, 0xf, true));  // row_shr:1
  x += __int_as_float(__builtin_amdgcn_update_dpp(0, __float_as_int(x), 0x112, 0xf, 0xf, true));  // row_shr:2
  x += __int_as_float(__builtin_amdgcn_update_dpp(0, __float_as_int(x), 0x114, 0xf, 0xf, true));  // row_shr:4
  x += __int_as_float(__builtin_amdgcn_update_dpp(0, __float_as_int(x), 0x118, 0xf, 0xf, true));  // row_shr:8
  x += __int_as_float(__builtin_amdgcn_update_dpp(0, __float_as_int(x), 0x142, 0xa, 0xf, false)); // row_bcast:15
  x += __int_as_float(__builtin_amdgcn_update_dpp(0, __float_as_int(x), 0x143, 0xc, 0xf, false)); // row_bcast:31
  return x;
}

#define NSTREAM 16   // 8 pred slots + 8 gt slots
#define CHUNK   512  // floats per stream per pipeline step (2 KB)
#define GRIDX   16   // blocks per batch

// ---------------------------------------------------------------------------
// Kernel 1: double-buffered async-DMA streaming reduction.
// Rounds 1/3 showed 48 us invariant to grid shape with ALL pipes idle ->
// vmem-latency serialization (16 scattered streams, consumption-dependent
// loads, no software pipelining possible at 132 VGPRs). Here: each wave DMAs
// 4 contiguous streams per step straight into LDS (global_load_lds, 16B),
// double-buffered; manual s_waitcnt vmcnt(8) + raw s_barrier keep the next
// step's 8 DMAs in flight across the barrier (no vmcnt(0) drain).
// Per batch b, block writes 66 partials:
//   [0] bg inter; [1+p*7+g] fg inter; [50+s] pred sums; [58+s] gt sums.
// ---------------------------------------------------------------------------
__global__ __launch_bounds__(256) void msl_accum(const float* __restrict__ pred,
                                                 const float* __restrict__ gt,
                                                 float* __restrict__ part, int HW) {
  __shared__ float smem[2 * NSTREAM * CHUNK];   // 64 KB, 2 buffers
  __shared__ float red[4][66];

  const int b    = blockIdx.y;
  const int bx   = blockIdx.x;
  const int tid  = threadIdx.x;
  const int wave = tid >> 6;
  const int lane = tid & 63;

  const size_t base   = (size_t)b * 8 * (size_t)HW;
  const int    region = bx * (HW / GRIDX);          // float offset in each stream
  const int    steps  = HW / (GRIDX * CHUNK);       // 8

  // Stream S: 0..7 = pred slot S, 8..15 = gt slot S-8. Wave w stages [4w,4w+4).
  const float* sbase[4];
#pragma unroll
  for (int k = 0; k < 4; ++k) {
    const int S = wave * 4 + k;
    const float* src = (S < 8) ? (pred + base + (size_t)S * HW)
                               : (gt   + base + (size_t)(S - 8) * HW);
    sbase[k] = src + region;
  }

  // One step = 8 DMA calls/wave (4 streams x 2 x 1KB). gptr carries lane*16B;
  // LDS dest is wave-uniform (HW adds lane*16 itself — m104/m108 caveat).
  auto issue = [&](int step, int bufIdx) {
#pragma unroll
    for (int k = 0; k < 4; ++k) {
      const int S = wave * 4 + k;
#pragma unroll
      for (int c = 0; c < 2; ++c) {
        const float* gp = sbase[k] + step * CHUNK + c * 256 + lane * 4;
        float* lp = &smem[bufIdx * (NSTREAM * CHUNK) + S * CHUNK + c * 256];
        __builtin_amdgcn_global_load_lds(
            (const __attribute__((address_space(1))) void*)gp,
            (__attribute__((address_space(3))) void*)lp, 16, 0, 0);
      }
    }
  };

  float a_bg = 0.0f;
  float af[7][7];
  float sp[8], sg[8];
#pragma unroll
  for (int p = 0; p < 7; ++p)
#pragma unroll
    for (int g = 0; g < 7; ++g) af[p][g] = 0.0f;
#pragma unroll
  for (int s = 0; s < 8; ++s) { sp[s] = 0.0f; sg[s] = 0.0f; }

  issue(0, 0);
  for (int k = 0; k < steps; ++k) {
    if (k + 1 < steps) {
      issue(k + 1, (k + 1) & 1);                    // prefetch next buffer
      __builtin_amdgcn_s_waitcnt(0x0F78);           // vmcnt(8): my step-k DMAs done
    } else {
      __builtin_amdgcn_s_waitcnt(0x0F70);           // vmcnt(0): final drain
    }
    asm volatile("" ::: "memory");
    __builtin_amdgcn_s_barrier();                   // raw barrier: no forced drain
    asm volatile("" ::: "memory");

    const float* buf = &smem[(k & 1) * (NSTREAM * CHUNK)];
    const int j = tid * 2;                          // 2 positions per thread
    float2 pv[8], gv[8];
#pragma unroll
    for (int s = 0; s < 8; ++s) pv[s] = *(const float2*)&buf[s * CHUNK + j];
#pragma unroll
    for (int s = 0; s < 8; ++s) gv[s] = *(const float2*)&buf[(8 + s) * CHUNK + j];

#pragma unroll
    for (int s = 0; s < 8; ++s) {
      sp[s] += pv[s].x + pv[s].y;
      sg[s] += gv[s].x + gv[s].y;
    }
    a_bg += pv[0].x * gv[0].x + pv[0].y * gv[0].y;
#pragma unroll
    for (int p = 0; p < 7; ++p)
#pragma unroll
      for (int g = 0; g < 7; ++g)
        af[p][g] += pv[p + 1].x * gv[g + 1].x + pv[p + 1].y * gv[g + 1].y;

    asm volatile("" ::: "memory");
    __builtin_amdgcn_s_barrier();                   // protect buf before step k+2 DMA
    asm volatile("" ::: "memory");
  }

  float v[66];
  v[0] = a_bg;
#pragma unroll
  for (int p = 0; p < 7; ++p)
#pragma unroll
    for (int g = 0; g < 7; ++g) v[1 + p * 7 + g] = af[p][g];
#pragma unroll
  for (int s = 0; s < 8; ++s) { v[50 + s] = sp[s]; v[58 + s] = sg[s]; }

#pragma unroll
  for (int kk = 0; kk < 66; ++kk) {
    float x = wave_sum_to_lane63(v[kk]);
    if (lane == 63) red[wave][kk] = x;
  }
  __syncthreads();

  const int row = blockIdx.y * gridDim.x + blockIdx.x;
  if (tid < 66) {
    float s = red[0][tid] + red[1][tid] + red[2][tid] + red[3][tid];
    part[row * 66 + tid] = s;                       // private row — no atomics
  }
}

// ---------------------------------------------------------------------------
// Kernel 2: finalize. One block, 32 lanes per batch. Sums partial rows,
// builds dice[p][g], computes the optimal-assignment VALUE via bitmask DP
// (the Hungarian match is only consumed through the sum of matched dice).
// ---------------------------------------------------------------------------
__global__ __launch_bounds__(1024) void msl_final(const float* __restrict__ part,
                                                  const int* __restrict__ nobj,
                                                  float* __restrict__ out,
                                                  int B, int RPB) {
  __shared__ float a[32][68];
  __shared__ float dp[32][130];
  __shared__ float dice[32][52];
  __shared__ float r_bg[32];
  __shared__ float r_ds[32];
  __shared__ int   r_n[32];

  const int batch = threadIdx.x >> 5;
  const int lane  = threadIdx.x & 31;
  const bool act  = (batch < B);

  if (act) {
    for (int k = lane; k < 66; k += 32) {
      float s = 0.0f;
#pragma unroll 4
      for (int r = 0; r < RPB; ++r) s += part[(batch * RPB + r) * 66 + k];
      a[batch][k] = s;
    }
  }
  __syncthreads();

  if (act) {
    for (int k = lane; k < 49; k += 32) {
      int p = k / 7, g = k % 7;
      dice[batch][k] = (2.0f * a[batch][1 + k] + EPSF) /
                       (a[batch][51 + p] + a[batch][59 + g] + EPSF);
    }
    if (lane == 0) {
      float u = a[batch][50] + a[batch][58];
      r_bg[batch] = 1.0f - (2.0f * a[batch][0] + EPSF) / (u + EPSF);
      int n = nobj[batch];
      n = n < 0 ? 0 : (n > 7 ? 7 : n);
      r_n[batch] = n;
      r_ds[batch] = 0.0f;
      dp[batch][0] = 0.0f;
    }
  }
  __syncthreads();
  const int n = act ? r_n[batch] : 0;

  for (int c = 1; c <= 7; ++c) {
    if (act && c <= n) {
      for (int mask = lane; mask < 128; mask += 32) {
        if (__popc(mask) == c) {
          float best = -1e30f;
#pragma unroll
          for (int r = 0; r < 7; ++r) {
            if (mask & (1 << r)) {
              float cand = dp[batch][mask ^ (1 << r)] + dice[batch][r * 7 + (c - 1)];
              best = fmaxf(best, cand);
            }
          }
          dp[batch][mask] = best;
        }
      }
    }
    __syncthreads();
  }

  float best = -1e30f;
  if (act && n > 0) {
    for (int mask = lane; mask < 128; mask += 32)
      if (__popc(mask) == n) best = fmaxf(best, dp[batch][mask]);
  }
#pragma unroll
  for (int off = 16; off > 0; off >>= 1)
    best = fmaxf(best, __shfl_down(best, off, 32));
  if (act && lane == 0 && n > 0) r_ds[batch] = best;
  __syncthreads();

  if (threadIdx.x == 0) {
    float bg = 0.0f, ds = 0.0f;
    int cnt = 0;
    for (int b = 0; b < B; ++b) { bg += r_bg[b]; ds += r_ds[b]; cnt += r_n[b]; }
    float fg = cnt > 0 ? ((float)cnt - ds) / (float)cnt : 0.0f;
    out[0] = bg / (float)B + fg;
  }
}

// ---------------------------------------------------------------------------
extern "C" void kernel_launch(void* const* d_in, const int* in_sizes, int n_in,
                              void* d_out, int out_size, void* d_ws, size_t ws_size,
                              hipStream_t stream) {
  const float* pred = (const float*)d_in[0];
  const float* gt   = (const float*)d_in[1];
  const int*   nobj = (const int*)d_in[2];
  float* out = (float*)d_out;

  const int B  = in_sizes[2];              // 32
  const int HW = in_sizes[0] / (B * 8);    // 65536

  float* part = (float*)d_ws;              // B * GRIDX * 66 floats

  // 512 blocks, 64 KB LDS -> 2 blocks/CU all co-resident; 8 pipeline steps
  // of 32 KB DMA each, double-buffered.
  msl_accum<<<dim3(GRIDX, B), dim3(256), 0, stream>>>(pred, gt, part, HW);

  msl_final<<<dim3(1), dim3(32 * B), 0, stream>>>(part, nobj, out, B, GRIDX);
}